// Round 12
// baseline (297.801 us; speedup 1.0000x reference)
//
#include <hip/hip_runtime.h>

#define S_LEN 2048
#define HID   1024
#define NHEAD 16
#define NKVH  4
#define HDIM  64
#define QKSTR 1280   // qkv buffer row stride: Q(1024) + K(256); V goes to vT transposed

typedef __bf16 bf16x8 __attribute__((ext_vector_type(8)));
typedef __bf16 bf16x4 __attribute__((ext_vector_type(4)));
typedef float  f32x4  __attribute__((ext_vector_type(4)));
typedef short  s16x4  __attribute__((ext_vector_type(4)));

// scale = (1/sqrt(1024)) * log2(e): fold softmax scale + base-2 conversion into Q
#define QSCALE 0.04508422f

__device__ __forceinline__ unsigned short f2bf(float f) {
    unsigned u = __builtin_bit_cast(unsigned, f);
    u = u + 0x7FFFu + ((u >> 16) & 1u);   // round-to-nearest-even
    return (unsigned short)(u >> 16);
}

__device__ __forceinline__ bf16x8 cvt8(float4 a, float4 b) {   // RNE, == f2bf bits
    bf16x8 r;
    r[0] = (__bf16)a.x; r[1] = (__bf16)a.y; r[2] = (__bf16)a.z; r[3] = (__bf16)a.w;
    r[4] = (__bf16)b.x; r[5] = (__bf16)b.y; r[6] = (__bf16)b.z; r[7] = (__bf16)b.w;
    return r;
}

// 16x16x16 bf16 MFMA (K=16): B-layout k = quad*4+j matches the S^T output
// granularity exactly -> softmax feeds PV with zero cross-lane movement.
__device__ __forceinline__ f32x4 mfma_16x16x16_bf16(s16x4 a, s16x4 b, f32x4 c) {
#if __has_builtin(__builtin_amdgcn_mfma_f32_16x16x16bf16_1k)
    return __builtin_amdgcn_mfma_f32_16x16x16bf16_1k(a, b, c, 0, 0, 0);
#else
    f32x4 d = c;
    asm volatile("s_nop 1\n\tv_mfma_f32_16x16x16_bf16 %0, %1, %2, %0\n\ts_nop 3"
                 : "+v"(d) : "v"(a), "v"(b));
    return d;
#endif
}

// ---------------- QKV projection, fused fp32->bf16 conversion (R9, passed) ----------------
// R11 addition: block (0,0) zeroes the 512 split-k tickets for attn's fused
// combine (kernel-boundary ordering makes them visible to attn).
__global__ __launch_bounds__(256, 2) void proj_gemm(
    const float* __restrict__ x,  const float* __restrict__ wq,
    const float* __restrict__ wk, const float* __restrict__ wv,
    unsigned short* __restrict__ qkv,
    unsigned short* __restrict__ vT,
    unsigned int* __restrict__ flags)
{
    __shared__ unsigned short At[2][64 * 64];
    __shared__ unsigned short Bt[2][96 * 64];
    const int tid = threadIdx.x;
    const int w = tid >> 6, l = tid & 63;
    const int quad = l >> 4, lane16 = l & 15;
    const int m0 = blockIdx.y * 64, n0 = blockIdx.x * 96;
    const int wm = (w & 1) * 32, wn = (w >> 1) * 48;

    if (blockIdx.x == 0 && blockIdx.y == 0) {   // zero split-k tickets
        flags[tid] = 0u;
        flags[256 + tid] = 0u;
    }

    const int srow = l >> 3;
    const int scol = ((l & 7) ^ srow) * 8;   // swizzled global col group
    const int dcol = (l & 7) * 8;            // linear LDS dest col group

    f32x4 acc[2][3] = {};
    float4 arA[2][2], arB[3][2];

    #define PLOAD(KT)                                                                   \
        do {                                                                            \
            _Pragma("unroll")                                                           \
            for (int c = 0; c < 2; ++c) {                                               \
                const float* ga = x + (long)(m0 + w * 16 + c * 8 + srow) * HID          \
                                    + (KT) + scol;                                      \
                arA[c][0] = ((const float4*)ga)[0];                                     \
                arA[c][1] = ((const float4*)ga)[1];                                     \
            }                                                                           \
            _Pragma("unroll")                                                           \
            for (int c = 0; c < 3; ++c) {                                               \
                const int row = n0 + w * 24 + c * 8 + srow;                             \
                const float* gb = (row < 1024) ? wq + (long)row * HID                   \
                                : (row < 1280) ? wk + (long)(row - 1024) * HID          \
                                               : wv + (long)(row - 1280) * HID;         \
                gb += (KT) + scol;                                                      \
                arB[c][0] = ((const float4*)gb)[0];                                     \
                arB[c][1] = ((const float4*)gb)[1];                                     \
            }                                                                           \
        } while (0)

    #define PWRITE(BUF)                                                                 \
        do {                                                                            \
            _Pragma("unroll")                                                           \
            for (int c = 0; c < 2; ++c)                                                 \
                *(bf16x8*)&At[BUF][(w * 16 + c * 8 + srow) * 64 + dcol] =               \
                    cvt8(arA[c][0], arA[c][1]);                                         \
            _Pragma("unroll")                                                           \
            for (int c = 0; c < 3; ++c)                                                 \
                *(bf16x8*)&Bt[BUF][(w * 24 + c * 8 + srow) * 64 + dcol] =               \
                    cvt8(arB[c][0], arB[c][1]);                                         \
        } while (0)

    PLOAD(0);

    for (int i = 0; i < 16; ++i) {
        const int cur = i & 1;
        PWRITE(cur);                    // waits on loads (had a full phase to fly)
        __syncthreads();
        if (i + 1 < 16) PLOAD((i + 1) * 64);   // issue after barrier; flies below

        #pragma unroll
        for (int ks = 0; ks < 2; ++ks) {
            const int swz = ((ks * 4 + quad) ^ (lane16 & 7)) * 8;
            bf16x8 a[2], b[3];
            #pragma unroll
            for (int mi = 0; mi < 2; ++mi)
                a[mi] = *(const bf16x8*)&At[cur][(wm + mi * 16 + lane16) * 64 + swz];
            #pragma unroll
            for (int ni = 0; ni < 3; ++ni)
                b[ni] = *(const bf16x8*)&Bt[cur][(wn + ni * 16 + lane16) * 64 + swz];
            #pragma unroll
            for (int mi = 0; mi < 2; ++mi)
                #pragma unroll
                for (int ni = 0; ni < 3; ++ni)
                    acc[mi][ni] = __builtin_amdgcn_mfma_f32_16x16x32_bf16(a[mi], b[ni], acc[mi][ni], 0, 0, 0);
        }
    }
    #undef PLOAD
    #undef PWRITE

    #pragma unroll
    for (int mi = 0; mi < 2; ++mi) {
        const int row = m0 + wm + mi * 16 + quad * 4;
        #pragma unroll
        for (int ni = 0; ni < 3; ++ni) {
            const int col = n0 + wn + ni * 16 + lane16;
            #pragma unroll
            for (int r = 0; r < 4; ++r) {
                const float v = acc[mi][ni][r];
                if (col < 1024)
                    qkv[(long)(row + r) * QKSTR + col] = f2bf(v * QSCALE);
                else if (col < 1280)
                    qkv[(long)(row + r) * QKSTR + col] = f2bf(v);
                else
                    vT[(long)(col - 1280) * S_LEN + (row + r)] = f2bf(v);
            }
        }
    }
}

// ---------------- flash attention, KV-SPLIT + FUSED COMBINE, causal, GQA ----------------
// R11 (resubmit; prior round was a GPU-acquisition timeout): same split
// structure as R10 (grid 32x16x2 = 1024 blocks, 4 blocks/CU, 16 waves/CU;
// exact no-max exp2 partials). The separate combine kernel is replaced by a
// split-k fixup INSIDE attn: each block stores its unnormalized partial +
// rsum, __threadfence (release), atomicAdd on the (qt,h) ticket. The block
// drawing ticket 1 is the finisher: fence (acquire), read partner's 16KB
// slice + partner r (own partial still in regs), add, normalize by r0+r1,
// store out. Bit-identical to the combine kernel's arithmetic; saves one
// launch + ~17MB of combine traffic. No spinning -> no deadlock; atomics
// are device-scope (m20); ticket zeroing done by proj (prior kernel).
#define KSTR 72   // LDS row stride (ushorts): multiple of 8 -> 16B-aligned b128
__global__ __launch_bounds__(256, 4) void attn(
    const unsigned short* __restrict__ qkv,
    const unsigned short* __restrict__ vT,
    float* __restrict__ opart,       // [2][2048][1024] f32 (unnormalized partials)
    float* __restrict__ rpart,       // [2][16][2048]  f32
    unsigned int* __restrict__ flags,// [16*32] tickets
    float* __restrict__ out)
{
    __shared__ unsigned short Kt[2][64 * KSTR];     // K tile  [kv][d]
    __shared__ unsigned short Vt[2][64 * KSTR];     // V^T tile [d][kv]
    __shared__ int ticket_s;

    const int tid = threadIdx.x;
    const int w = tid >> 6, l = tid & 63;
    const int quad = l >> 4, lane16 = l & 15;
    const int bx = blockIdx.x, by = blockIdx.y, bz = blockIdx.z;
    const int qt = (by & 8) ? (31 - bx) : bx;       // balanced pairing remap
    const int h  = by;
    const int kh = h >> 2;
    const int qcol = h * 64;
    const int kcol = 1024 + kh * 64;

    const int nt  = qt + 1;                         // total KV tiles for this qt
    const int h1  = (nt + 1) >> 1;                  // split point
    const int tlo = bz ? h1 : 0;
    const int thi = bz ? nt : h1;

    // Q fragments (B-layout: n=lane16, k=quad*8+j), Q pre-scaled by proj_gemm
    const long qrow = (long)(qt * 64 + w * 16 + lane16);
    bf16x8 qa0 = *(const bf16x8*)&qkv[qrow * QKSTR + qcol + quad * 8];
    bf16x8 qa1 = *(const bf16x8*)&qkv[qrow * QKSTR + qcol + 32 + quad * 8];

    f32x4 oT[4] = {};                // O^T: oT[dt][r] = O[q=lane16][d=dt*16+quad*4+r]
    float rsum[4] = {0.f, 0.f, 0.f, 0.f};

    // staging coords: 256 thr x 16 ushorts cover each 64x64 tile
    const int sr = tid >> 2, ss = tid & 3;
    const long vrow = (long)(kh * 64 + sr) * S_LEN;

    bf16x8 kr0, kr1, vr0, vr1;
    if (tlo < thi) {                                // prologue: prefetch tile tlo
        const long gk = (long)(tlo * 64 + sr) * QKSTR + kcol + ss * 16;
        kr0 = *(const bf16x8*)&qkv[gk];
        kr1 = *(const bf16x8*)&qkv[gk + 8];
        const long gv = vrow + tlo * 64 + ss * 16;
        vr0 = *(const bf16x8*)&vT[gv];
        vr1 = *(const bf16x8*)&vT[gv + 8];
    }

    for (int kt = tlo; kt < thi; ++kt) {
        const int cur = kt & 1;
        // (A) store prefetched tile into buf[cur]
        *(bf16x8*)&Kt[cur][sr * KSTR + ss * 16]     = kr0;
        *(bf16x8*)&Kt[cur][sr * KSTR + ss * 16 + 8] = kr1;
        *(bf16x8*)&Vt[cur][sr * KSTR + ss * 16]     = vr0;
        *(bf16x8*)&Vt[cur][sr * KSTR + ss * 16 + 8] = vr1;

        __syncthreads();                      // (B) staging[cur] visible

        // issue kt+1 prefetch after the barrier (flies during compute below)
        if (kt + 1 < thi) {
            const long gk = (long)((kt + 1) * 64 + sr) * QKSTR + kcol + ss * 16;
            kr0 = *(const bf16x8*)&qkv[gk];
            kr1 = *(const bf16x8*)&qkv[gk + 8];
            const long gv = vrow + (kt + 1) * 64 + ss * 16;
            vr0 = *(const bf16x8*)&vT[gv];
            vr1 = *(const bf16x8*)&vT[gv + 8];
        }

        // S^T = K Q^T  (64 kv x 16 q-rows); C: row=kv=t*16+quad*4+r, col=lane16
        f32x4 sacc[4] = {};
        __builtin_amdgcn_s_setprio(1);
        #pragma unroll
        for (int t = 0; t < 4; ++t) {
            bf16x8 kb0 = *(const bf16x8*)&Kt[cur][(t * 16 + lane16) * KSTR + quad * 8];
            bf16x8 kb1 = *(const bf16x8*)&Kt[cur][(t * 16 + lane16) * KSTR + 32 + quad * 8];
            sacc[t] = __builtin_amdgcn_mfma_f32_16x16x32_bf16(kb0, qa0, sacc[t], 0, 0, 0);
            sacc[t] = __builtin_amdgcn_mfma_f32_16x16x32_bf16(kb1, qa1, sacc[t], 0, 0, 0);
        }
        __builtin_amdgcn_s_setprio(0);

        // causal mask on diagonal tile: kv > qrow  (both local to this 64-block)
        if (kt == qt) {
            #pragma unroll
            for (int t = 0; t < 4; ++t) {
                const int kvw = t * 16 + quad * 4;
                #pragma unroll
                for (int r = 0; r < 4; ++r)
                    if (kvw + r > w * 16 + lane16) sacc[t][r] = -3.0e38f;
            }
        }

        // softmax: p = exp2(s); lane's 4 values per t ARE the 16x16x16 B-frag
        s16x4 pfrag[4];
        #pragma unroll
        for (int t = 0; t < 4; ++t) {
            const float p0 = __builtin_amdgcn_exp2f(sacc[t][0]);
            const float p1 = __builtin_amdgcn_exp2f(sacc[t][1]);
            const float p2 = __builtin_amdgcn_exp2f(sacc[t][2]);
            const float p3 = __builtin_amdgcn_exp2f(sacc[t][3]);
            rsum[t] += (p0 + p1) + (p2 + p3);
            bf16x4 pk;
            pk[0] = (__bf16)p0; pk[1] = (__bf16)p1;
            pk[2] = (__bf16)p2; pk[3] = (__bf16)p3;
            pfrag[t] = __builtin_bit_cast(s16x4, pk);
        }

        // O^T += V^T P^T  (A = V^T 4 contiguous bf16, b64 read)
        __builtin_amdgcn_s_setprio(1);
        #pragma unroll
        for (int dt = 0; dt < 4; ++dt)
            #pragma unroll
            for (int t = 0; t < 4; ++t) {
                bf16x4 va = *(const bf16x4*)&Vt[cur][(dt * 16 + lane16) * KSTR + t * 16 + quad * 4];
                oT[dt] = mfma_16x16x16_bf16(__builtin_bit_cast(s16x4, va), pfrag[t], oT[dt]);
            }
        __builtin_amdgcn_s_setprio(0);
    }

    // partial rowsum for q = lane16 (all lanes hold their row's total copy)
    float total = (rsum[0] + rsum[1]) + (rsum[2] + rsum[3]);
    total += __shfl_xor(total, 16);
    total += __shfl_xor(total, 32);

    // ---- write partial (unnormalized) + r ----
    float* op = opart + (long)bz * S_LEN * (NHEAD * HDIM);
    #pragma unroll
    for (int dt = 0; dt < 4; ++dt) {
        const int col = h * 64 + dt * 16 + quad * 4;
        float4 v; v.x = oT[dt][0]; v.y = oT[dt][1]; v.z = oT[dt][2]; v.w = oT[dt][3];
        *(float4*)&op[qrow * (NHEAD * HDIM) + col] = v;
    }
    if (l < 16)
        rpart[(long)bz * NHEAD * S_LEN + (long)h * S_LEN + qrow] = total;

    // ---- split-k fixup: last block of the (qt,h) pair combines ----
    __threadfence();                               // release: partial visible
    if (tid == 0)
        ticket_s = (int)atomicAdd(&flags[by * 32 + bx], 1u);
    __syncthreads();
    if (ticket_s == 1) {                           // we are the finisher
        __threadfence();                           // acquire: partner visible
        const float* pop = opart + (long)(bz ^ 1) * S_LEN * (NHEAD * HDIM);
        const float r2 = rpart[(long)(bz ^ 1) * NHEAD * S_LEN + (long)h * S_LEN + qrow];
        const float inv = 1.0f / (total + r2);
        #pragma unroll
        for (int dt = 0; dt < 4; ++dt) {
            const int col = h * 64 + dt * 16 + quad * 4;
            const float4 pv = *(const float4*)&pop[qrow * (NHEAD * HDIM) + col];
            float4 o;
            o.x = (oT[dt][0] + pv.x) * inv;
            o.y = (oT[dt][1] + pv.y) * inv;
            o.z = (oT[dt][2] + pv.z) * inv;
            o.w = (oT[dt][3] + pv.w) * inv;
            *(float4*)&out[qrow * (NHEAD * HDIM) + col] = o;
        }
    }
}

extern "C" void kernel_launch(void* const* d_in, const int* in_sizes, int n_in,
                              void* d_out, int out_size, void* d_ws, size_t ws_size,
                              hipStream_t stream) {
    const float* x  = (const float*)d_in[0];
    const float* wq = (const float*)d_in[1];
    const float* wk = (const float*)d_in[2];
    const float* wv = (const float*)d_in[3];
    float* out = (float*)d_out;

    unsigned short* qkv = (unsigned short*)d_ws;                 // 2048*1280 (Q+K)
    unsigned short* vT  = qkv + (size_t)S_LEN * QKSTR;           // 256*2048  (V^T)
    float* opart = (float*)(vT + (size_t)256 * S_LEN);           // 2*2048*1024 f32
    float* rpart = opart + (size_t)2 * S_LEN * (NHEAD * HDIM);   // 2*16*2048  f32
    unsigned int* flags = (unsigned int*)(rpart + (size_t)2 * NHEAD * S_LEN); // 512 u32

    proj_gemm<<<dim3(16, 32), dim3(256), 0, stream>>>(x, wq, wk, wv, qkv, vT, flags);
    attn<<<dim3(32, 16, 2), dim3(256), 0, stream>>>(qkv, vT, opart, rpart, flags, out);
}